// Round 19
// baseline (6517.316 us; speedup 1.0000x reference)
//
#include <hip/hip_runtime.h>
#include <math.h>

#define HID 51
#define TMAIN 1024
#define FUT 64
#define TT (TMAIN + FUT)
#define RING 128   // h2 history ring depth (pow2)
#define RPAD 68    // ring row stride in floats (16B-aligned, bank-skewed)

typedef float v2f __attribute__((ext_vector_type(2)));

__device__ __forceinline__ float fast_sigmoid(float x) {
  return 1.0f / (1.0f + __expf(-x));
}
__device__ __forceinline__ float fast_tanh(float x) {
  return 1.0f - 2.0f / (__expf(2.0f * x) + 1.0f);
}

// Single-seq packed full-K dot, 4 independent chains (2 gates x 2 k-halves).
// float4 LDS reads; h4[12] touches h[48..51] (element 51 loaded but unused).
__device__ __forceinline__ void dot1x(const float* h, const v2f (&w2)[2][25],
                                      const float (&w50)[2], float (&a)[2]) {
  const float4* h4 = reinterpret_cast<const float4*>(h);
  v2f s0a = {0.f, 0.f}, s0b = {0.f, 0.f};
  v2f s1a = {0.f, 0.f}, s1b = {0.f, 0.f};
#pragma unroll
  for (int q = 0; q < 6; ++q) {
    float4 hv = h4[q];
    v2f lo = {hv.x, hv.y}, hi = {hv.z, hv.w};
    s0a = __builtin_elementwise_fma(lo, w2[0][2 * q + 0], s0a);
    s1a = __builtin_elementwise_fma(lo, w2[1][2 * q + 0], s1a);
    s0a = __builtin_elementwise_fma(hi, w2[0][2 * q + 1], s0a);
    s1a = __builtin_elementwise_fma(hi, w2[1][2 * q + 1], s1a);
  }
#pragma unroll
  for (int q = 6; q < 12; ++q) {
    float4 hv = h4[q];
    v2f lo = {hv.x, hv.y}, hi = {hv.z, hv.w};
    s0b = __builtin_elementwise_fma(lo, w2[0][2 * q + 0], s0b);
    s1b = __builtin_elementwise_fma(lo, w2[1][2 * q + 0], s1b);
    s0b = __builtin_elementwise_fma(hi, w2[0][2 * q + 1], s0b);
    s1b = __builtin_elementwise_fma(hi, w2[1][2 * q + 1], s1b);
  }
  float4 ht = h4[12];
  v2f lo = {ht.x, ht.y};
  s0b = __builtin_elementwise_fma(lo, w2[0][24], s0b);
  s1b = __builtin_elementwise_fma(lo, w2[1][24], s1b);
  a[0] = fmaf(ht.z, w50[0], a[0] + (s0a.x + s0a.y) + (s0b.x + s0b.y));
  a[1] = fmaf(ht.z, w50[1], a[1] + (s1a.x + s1a.y) + (s1b.x + s1b.y));
}

// Single-seq half-K dot: 13 float2 pairs from a pre-offset pointer, 4
// chains. K2 waves' pair 12 multiplies {h[50],h[51]} by {w50,0}; h1[51]==0.
__device__ __forceinline__ void dotH1(const float* h, const v2f (&w)[2][13],
                                      float (&a)[2]) {
  const float2* h2p = reinterpret_cast<const float2*>(h);
  v2f s0a = {0.f, 0.f}, s0b = {0.f, 0.f};
  v2f s1a = {0.f, 0.f}, s1b = {0.f, 0.f};
#pragma unroll
  for (int p = 0; p < 7; ++p) {
    float2 hv = h2p[p];
    v2f x = {hv.x, hv.y};
    s0a = __builtin_elementwise_fma(x, w[0][p], s0a);
    s1a = __builtin_elementwise_fma(x, w[1][p], s1a);
  }
#pragma unroll
  for (int p = 7; p < 13; ++p) {
    float2 hv = h2p[p];
    v2f x = {hv.x, hv.y};
    s0b = __builtin_elementwise_fma(x, w[0][p], s0b);
    s1b = __builtin_elementwise_fma(x, w[1][p], s1b);
  }
  a[0] = (s0a.x + s0a.y) + (s0b.x + s0b.y);
  a[1] = (s1a.x + s1a.y) + (s1b.x + s1b.y);
}

// One block = ONE sequence, 8 waves — the R18 pipeline with the dual-seq
// dimension dropped so TWO blocks co-reside per CU (R18: VALUBusy 52% at
// 1 block/CU -> ~48% of cycles idle on latency/barriers with nothing to
// fill them; a second independent block interleaves into those slots).
//   wid0,1: L1 cell, units [0,26)/[26,51)  [lane-half = gate pair]
//   wid2,3: Wh2 cell (L2), units [0,26)/[26,51) [carry c2; feedback lin]
//   wid4,5: Wi2 K[26,51) partial (+bias2 fold)  [wid4 also out-flush]
//   wid6,7: Wi2 K[0,26)  partial
// Pipeline skew (1 barrier/interval): h1(k) | piK(k-1) | h2(k-2).
// Linear head OUT of the loop: h2 in a 128-ring; every 64 intervals wid4
// computes+stores 64 outputs (plain dots). Feedback = 3-sub-phase serial.
// Resources: LDS ~44 KB, __launch_bounds__(512,4) caps VGPR at 128
// (R18 used 116 dual-seq; single-seq is smaller) -> 16 waves/CU.
__global__ __launch_bounds__(512, 4)
void lstm2_persistent(const float* __restrict__ input,
                      const float* __restrict__ Wi1,
                      const float* __restrict__ Wh1,
                      const float* __restrict__ bi1,
                      const float* __restrict__ bh1,
                      const float* __restrict__ Wi2,
                      const float* __restrict__ Wh2,
                      const float* __restrict__ bi2,
                      const float* __restrict__ bh2,
                      const float* __restrict__ Wlin,
                      const float* __restrict__ blin,
                      float* __restrict__ out) {
  __shared__ __align__(16) float lds_x[TMAIN];         // 4 KB
  __shared__ __align__(16) float lds_h1[2][64];        // [parity][u]
  __shared__ __align__(16) float lds_piK1[2][4][64];   // [par][g][u]
  __shared__ __align__(16) float lds_piK2[2][4][64];   // [par][g][u]
  __shared__ __align__(16) float lds_h2h[RING][RPAD];  // h2 history ring
  __shared__ __align__(16) float lds_wlin[64];
  __shared__ __align__(16) float lds_outbuf[64];       // feedback outputs
  __shared__ float lds_lin[2][2];                      // [par][cellwave]
  __shared__ float lds_fb[1];                          // out(1023) seed

  const int tid = threadIdx.x;
  const int s = blockIdx.x;  // sequence
  const int wid = tid >> 6;  // 0..7
  const int lane = tid & 63;
  const int half = lane >> 5;  // 0: gates {i,f}, 1: gates {g,o}
  const int l5 = lane & 31;
  const int base = (wid & 1) * 26;
  const int nu = (wid & 1) ? 25 : 26;
  const bool act = l5 < nu;
  const int u = base + (act ? l5 : 0);  // clamped unit index
  const int g0 = half * 2;
  const int koff = (wid >= 6) ? 0 : 26;  // Wi2 K-half offset

  // Stage input; zero h1 buffers (elems 51..63 too -> dotH1 pair-12 safe)
  // and ring slot RING-1 (h2(-1) = 0); stage wlin.
  for (int i = tid; i < TMAIN; i += 512) lds_x[i] = input[s * TMAIN + i];
  if (tid < 64) {
    lds_h1[0][tid] = 0.0f;
    lds_h1[1][tid] = 0.0f;
    lds_h2h[RING - 1][tid] = 0.0f;
    lds_wlin[tid] = (tid < HID) ? Wlin[tid] : 0.0f;
  }

  // ---- weights ----
  v2f w2f[2][25];  // full rows (L1 / Wh2 cell waves)
  float w50f[2] = {0.f, 0.f};
  v2f w2h[2][13];  // half rows (Wi2 waves)
  float bias[2] = {0.f, 0.f};
  float wi1g[2] = {0.f, 0.f};
  float wlin_u = 0.0f;
  float c1 = 0.0f;  // cell state (L1 in wid01, L2 in wid23)

  if (wid < 4) {
    const float* Wsel = (wid < 2) ? Wh1 : Wh2;
#pragma unroll
    for (int g = 0; g < 2; ++g) {
      const float* row = Wsel + ((g0 + g) * HID + u) * HID;
#pragma unroll
      for (int p = 0; p < 25; ++p) {
        v2f t;
        t.x = row[2 * p + 0];
        t.y = row[2 * p + 1];
        w2f[g][p] = t;
      }
      w50f[g] = row[50];
    }
    if (wid < 2) {
#pragma unroll
      for (int g = 0; g < 2; ++g) {
        bias[g] = bi1[(g0 + g) * HID + u] + bh1[(g0 + g) * HID + u];
        wi1g[g] = Wi1[(g0 + g) * HID + u];
      }
    } else {
      wlin_u = Wlin[u];  // feedback-phase butterfly weight
    }
#pragma unroll
    for (int g = 0; g < 2; ++g) {
#pragma unroll
      for (int p = 0; p < 25; ++p) asm volatile("" : "+v"(w2f[g][p]));
      asm volatile("" : "+v"(w50f[g]), "+v"(bias[g]), "+v"(wi1g[g]));
    }
    asm volatile("" : "+v"(wlin_u));
  } else {
#pragma unroll
    for (int g = 0; g < 2; ++g) {
      const float* row = Wi2 + ((g0 + g) * HID + u) * HID + koff;
      if (koff == 0) {
#pragma unroll
        for (int p = 0; p < 13; ++p) {
          v2f t;
          t.x = row[2 * p + 0];
          t.y = row[2 * p + 1];
          w2h[g][p] = t;
        }
      } else {
#pragma unroll
        for (int p = 0; p < 12; ++p) {
          v2f t;
          t.x = row[2 * p + 0];
          t.y = row[2 * p + 1];
          w2h[g][p] = t;
        }
        v2f t;
        t.x = row[24];  // K=50
        t.y = 0.0f;     // pairs with h1[51] == 0
        w2h[g][12] = t;
      }
    }
    if (koff == 26) {  // K2 waves carry bias2 (folded into piK2 writes)
#pragma unroll
      for (int g = 0; g < 2; ++g)
        bias[g] = bi2[(g0 + g) * HID + u] + bh2[(g0 + g) * HID + u];
    }
#pragma unroll
    for (int g = 0; g < 2; ++g) {
#pragma unroll
      for (int p = 0; p < 13; ++p) asm volatile("" : "+v"(w2h[g][p]));
      asm volatile("" : "+v"(bias[g]));
    }
  }
  const float blin_s = blin[0];

  __syncthreads();

  // =============== main-phase pipeline: one barrier per interval ========
  for (int k = 0; k <= TMAIN + 2; ++k) {
    if (wid < 2) {
      if (k < TMAIN) {
        // h1(k) = cell1(x(k), h1(k-1));  h1(m) lives in buffer (m+1)&1
        float x = lds_x[k];
        float a[2];
#pragma unroll
        for (int g = 0; g < 2; ++g) a[g] = fmaf(x, wi1g[g], bias[g]);
        dot1x(lds_h1[k & 1], w2f, w50f, a);
        float p0 = __shfl_xor(a[0], 32), p1 = __shfl_xor(a[1], 32);
        float gi = half ? p0 : a[0], gf = half ? p1 : a[1];
        float gg = half ? a[0] : p0, go = half ? a[1] : p1;
        c1 = fast_sigmoid(gf) * c1 + fast_sigmoid(gi) * fast_tanh(gg);
        float h = fast_sigmoid(go) * fast_tanh(c1);
        if (act && half == 0) lds_h1[(k + 1) & 1][u] = h;
      }
    } else if (wid < 4) {
      if (k >= 2 && k <= TMAIN + 1) {
        // h2(m2) = cell2(piK1(m2)+piK2(m2) + Wh2 @ h2(m2-1)); bias in piK2
        const int m2 = k - 2;
        const int pm = m2 & 1;
        float a[2];
        a[0] = lds_piK1[pm][g0 + 0][u] + lds_piK2[pm][g0 + 0][u];
        a[1] = lds_piK1[pm][g0 + 1][u] + lds_piK2[pm][g0 + 1][u];
        dot1x(&lds_h2h[(m2 - 1) & (RING - 1)][0], w2f, w50f, a);
        float p0 = __shfl_xor(a[0], 32), p1 = __shfl_xor(a[1], 32);
        float gi = half ? p0 : a[0], gf = half ? p1 : a[1];
        float gg = half ? a[0] : p0, go = half ? a[1] : p1;
        c1 = fast_sigmoid(gf) * c1 + fast_sigmoid(gi) * fast_tanh(gg);
        float h = fast_sigmoid(go) * fast_tanh(c1);
        if (act && half == 0) lds_h2h[m2 & (RING - 1)][u] = h;
      }
    } else {
      if (k >= 1 && k <= TMAIN) {
        // piK(k-1) partial: Wi2[:, koff:koff+26] @ h1(k-1)[koff:...]
        float a[2];
        dotH1(&lds_h1[k & 1][koff], w2h, a);
        const int pm = (k - 1) & 1;
        if (act) {
          if (koff == 26) {
            a[0] += bias[0];
            a[1] += bias[1];
            lds_piK2[pm][g0 + 0][u] = a[0];
            lds_piK2[pm][g0 + 1][u] = a[1];
          } else {
            lds_piK1[pm][g0 + 0][u] = a[0];
            lds_piK1[pm][g0 + 1][u] = a[1];
          }
        }
      }
      // Deferred linear head: every 64 intervals wid4 emits 64 outputs
      // (chunk c=k-66; h2(c+63) landed at interval c+65; writer this
      // interval touches slot (c+64)&127 -- disjoint from read slots).
      if (wid == 4 && k >= 66 && ((k - 66) & 63) == 0) {
        const int c = k - 66;
        const int m = c + lane;
        const float* r = &lds_h2h[m & (RING - 1)][0];
        const float4* r4 = reinterpret_cast<const float4*>(r);
        const float4* w4 = reinterpret_cast<const float4*>(lds_wlin);
        float o0 = 0.f, o1 = 0.f, o2 = 0.f, o3 = 0.f;
#pragma unroll
        for (int q = 0; q < 12; ++q) {
          float4 rv = r4[q];
          float4 wv = w4[q];
          o0 = fmaf(rv.x, wv.x, o0);
          o1 = fmaf(rv.y, wv.y, o1);
          o2 = fmaf(rv.z, wv.z, o2);
          o3 = fmaf(rv.w, wv.w, o3);
        }
        o0 = fmaf(r[48], lds_wlin[48], o0);
        o1 = fmaf(r[49], lds_wlin[49], o1);
        o2 = fmaf(r[50], lds_wlin[50], o2);
        float o = (o0 + o1) + (o2 + o3) + blin_s;
        out[s * TT + m] = o;
        if (m == TMAIN - 1) lds_fb[0] = o;  // feedback seed
      }
    }
    __syncthreads();
  }

  // =============== feedback phase: 3 sub-phases, barriered ==============
  for (int t = TMAIN; t < TT; ++t) {
    float ph[2] = {0.f, 0.f};
    // --- A: L1 cell with feedback x; cell waves pre-dot Wh2 @ h2(t-1) ---
    if (wid < 2) {
      float o;
      if (t == TMAIN) {
        o = lds_fb[0];
      } else {
        o = lds_lin[(t - 1) & 1][0] + lds_lin[(t - 1) & 1][1] + blin_s;
        if (wid == 0 && lane == 0) lds_outbuf[t - 1 - TMAIN] = o;
      }
      float a[2];
#pragma unroll
      for (int g = 0; g < 2; ++g) a[g] = fmaf(o, wi1g[g], bias[g]);
      dot1x(lds_h1[t & 1], w2f, w50f, a);
      float p0 = __shfl_xor(a[0], 32), p1 = __shfl_xor(a[1], 32);
      float gi = half ? p0 : a[0], gf = half ? p1 : a[1];
      float gg = half ? a[0] : p0, go = half ? a[1] : p1;
      c1 = fast_sigmoid(gf) * c1 + fast_sigmoid(gi) * fast_tanh(gg);
      float h = fast_sigmoid(go) * fast_tanh(c1);
      if (act && half == 0) lds_h1[(t + 1) & 1][u] = h;
    } else if (wid < 4) {
      dot1x(&lds_h2h[(t - 1) & (RING - 1)][0], w2f, w50f, ph);
    }
    __syncthreads();
    // --- B: piK halves from h1(t) ---
    if (wid >= 4) {
      float a[2];
      dotH1(&lds_h1[(t + 1) & 1][koff], w2h, a);
      const int pm = t & 1;
      if (act) {
        if (koff == 26) {
          a[0] += bias[0];
          a[1] += bias[1];
          lds_piK2[pm][g0 + 0][u] = a[0];
          lds_piK2[pm][g0 + 1][u] = a[1];
        } else {
          lds_piK1[pm][g0 + 0][u] = a[0];
          lds_piK1[pm][g0 + 1][u] = a[1];
        }
      }
    }
    __syncthreads();
    // --- C: L2 cell + linear head (butterfly on cell waves here) ---
    if (wid >= 2 && wid < 4) {
      const int pm = t & 1;
      float a[2];
      a[0] = lds_piK1[pm][g0 + 0][u] + lds_piK2[pm][g0 + 0][u] + ph[0];
      a[1] = lds_piK1[pm][g0 + 1][u] + lds_piK2[pm][g0 + 1][u] + ph[1];
      float p0 = __shfl_xor(a[0], 32), p1 = __shfl_xor(a[1], 32);
      float gi = half ? p0 : a[0], gf = half ? p1 : a[1];
      float gg = half ? a[0] : p0, go = half ? a[1] : p1;
      c1 = fast_sigmoid(gf) * c1 + fast_sigmoid(gi) * fast_tanh(gg);
      float h = fast_sigmoid(go) * fast_tanh(c1);
      float val = 0.0f;
      if (act && half == 0) {
        lds_h2h[t & (RING - 1)][u] = h;
        val = wlin_u * h;
      }
#pragma unroll
      for (int off = 16; off >= 1; off >>= 1) val += __shfl_xor(val, off);
      if (lane == 0) lds_lin[t & 1][wid - 2] = val;
    }
    __syncthreads();
  }

  // epilogue: buffer out(TT-1), then flush the 64 future outputs
  if (wid == 0 && lane == 0) {
    float o = lds_lin[(TT - 1) & 1][0] + lds_lin[(TT - 1) & 1][1] + blin_s;
    lds_outbuf[63] = o;
  }
  __syncthreads();
  if (wid == 4) out[s * TT + TMAIN + lane] = lds_outbuf[lane];
}

extern "C" void kernel_launch(void* const* d_in, const int* in_sizes, int n_in,
                              void* d_out, int out_size, void* d_ws,
                              size_t ws_size, hipStream_t stream) {
  const float* input = (const float*)d_in[0];
  const float* Wi1 = (const float*)d_in[1];
  const float* Wh1 = (const float*)d_in[2];
  const float* bi1 = (const float*)d_in[3];
  const float* bh1 = (const float*)d_in[4];
  const float* Wi2 = (const float*)d_in[5];
  const float* Wh2 = (const float*)d_in[6];
  const float* bi2 = (const float*)d_in[7];
  const float* bh2 = (const float*)d_in[8];
  const float* Wlin = (const float*)d_in[9];
  const float* blin = (const float*)d_in[10];
  float* out = (float*)d_out;

  const int B = in_sizes[0] / TMAIN;  // 512
  lstm2_persistent<<<B, 512, 0, stream>>>(input, Wi1, Wh1, bi1, bh1, Wi2,
                                          Wh2, bi2, bh2, Wlin, blin, out);
}

// Round 21
// 1547.943 us; speedup vs baseline: 4.2103x; 4.2103x over previous
//
#include <hip/hip_runtime.h>
#include <math.h>

#define HID 51
#define TMAIN 1024
#define FUT 64
#define TT (TMAIN + FUT)
#define RING 128   // h2 history ring depth (pow2)
#define RPAD 68    // ring row stride in floats (16B-aligned, bank-skewed)

typedef float v2f __attribute__((ext_vector_type(2)));

__device__ __forceinline__ float fast_sigmoid(float x) {
  return 1.0f / (1.0f + __expf(-x));
}
__device__ __forceinline__ float fast_tanh(float x) {
  return 1.0f - 2.0f / (__expf(2.0f * x) + 1.0f);
}

// Single-seq packed full-K dot, 4 independent chains (2 gates x 2 k-halves).
// float4 LDS reads; h4[12] touches h[48..51] (element 51 loaded but unused).
__device__ __forceinline__ void dot1x(const float* h, const v2f (&w2)[2][25],
                                      const float (&w50)[2], float (&a)[2]) {
  const float4* h4 = reinterpret_cast<const float4*>(h);
  v2f s0a = {0.f, 0.f}, s0b = {0.f, 0.f};
  v2f s1a = {0.f, 0.f}, s1b = {0.f, 0.f};
#pragma unroll
  for (int q = 0; q < 6; ++q) {
    float4 hv = h4[q];
    v2f lo = {hv.x, hv.y}, hi = {hv.z, hv.w};
    s0a = __builtin_elementwise_fma(lo, w2[0][2 * q + 0], s0a);
    s1a = __builtin_elementwise_fma(lo, w2[1][2 * q + 0], s1a);
    s0a = __builtin_elementwise_fma(hi, w2[0][2 * q + 1], s0a);
    s1a = __builtin_elementwise_fma(hi, w2[1][2 * q + 1], s1a);
  }
#pragma unroll
  for (int q = 6; q < 12; ++q) {
    float4 hv = h4[q];
    v2f lo = {hv.x, hv.y}, hi = {hv.z, hv.w};
    s0b = __builtin_elementwise_fma(lo, w2[0][2 * q + 0], s0b);
    s1b = __builtin_elementwise_fma(lo, w2[1][2 * q + 0], s1b);
    s0b = __builtin_elementwise_fma(hi, w2[0][2 * q + 1], s0b);
    s1b = __builtin_elementwise_fma(hi, w2[1][2 * q + 1], s1b);
  }
  float4 ht = h4[12];
  v2f lo = {ht.x, ht.y};
  s0b = __builtin_elementwise_fma(lo, w2[0][24], s0b);
  s1b = __builtin_elementwise_fma(lo, w2[1][24], s1b);
  a[0] = fmaf(ht.z, w50[0], a[0] + (s0a.x + s0a.y) + (s0b.x + s0b.y));
  a[1] = fmaf(ht.z, w50[1], a[1] + (s1a.x + s1a.y) + (s1b.x + s1b.y));
}

// Single-seq half-K dot: 13 float2 pairs from a pre-offset pointer, 4
// chains. K2 waves' pair 12 multiplies {h[50],h[51]} by {w50,0}; h1[51]==0.
__device__ __forceinline__ void dotH1(const float* h, const v2f (&w)[2][13],
                                      float (&a)[2]) {
  const float2* h2p = reinterpret_cast<const float2*>(h);
  v2f s0a = {0.f, 0.f}, s0b = {0.f, 0.f};
  v2f s1a = {0.f, 0.f}, s1b = {0.f, 0.f};
#pragma unroll
  for (int p = 0; p < 7; ++p) {
    float2 hv = h2p[p];
    v2f x = {hv.x, hv.y};
    s0a = __builtin_elementwise_fma(x, w[0][p], s0a);
    s1a = __builtin_elementwise_fma(x, w[1][p], s1a);
  }
#pragma unroll
  for (int p = 7; p < 13; ++p) {
    float2 hv = h2p[p];
    v2f x = {hv.x, hv.y};
    s0b = __builtin_elementwise_fma(x, w[0][p], s0b);
    s1b = __builtin_elementwise_fma(x, w[1][p], s1b);
  }
  a[0] = (s0a.x + s0a.y) + (s0b.x + s0b.y);
  a[1] = (s1a.x + s1a.y) + (s1b.x + s1b.y);
}

// One block = ONE sequence, 8 waves; TWO blocks co-reside per CU.
// R19 lesson: the occupancy mechanism WORKS (48.2% measured) but the
// hard (512,4) reg cap triggered the allocator's cap-collapse (VGPR 64 +
// 21.5 GB scratch; same failure mode as R12/R13/R15/R16). R18 proved the
// identical dual-seq kernel allocates 116 regs under a soft (512,2) cap
// -- and 116 <= 128 means the HW grants 4 waves/SIMD anyway. R18's 1-block
// occupancy was LDS-limited (88 KB); this kernel's 44.5 KB LDS lets two
// blocks fit. So: soft cap, natural allocation, occupancy from resources.
// (R20 bench was an infra failure -- container died; identical resubmit.)
//   wid0,1: L1 cell, units [0,26)/[26,51)  [lane-half = gate pair]
//   wid2,3: Wh2 cell (L2), units [0,26)/[26,51) [carry c2; feedback lin]
//   wid4,5: Wi2 K[26,51) partial (+bias2 fold)  [wid4 also out-flush]
//   wid6,7: Wi2 K[0,26)  partial
// Pipeline skew (1 barrier/interval): h1(k) | piK(k-1) | h2(k-2).
// Linear head OUT of the loop: h2 in a 128-ring; every 64 intervals wid4
// computes+stores 64 outputs (plain dots). Feedback = 3-sub-phase serial.
__global__ __launch_bounds__(512, 2)
void lstm2_persistent(const float* __restrict__ input,
                      const float* __restrict__ Wi1,
                      const float* __restrict__ Wh1,
                      const float* __restrict__ bi1,
                      const float* __restrict__ bh1,
                      const float* __restrict__ Wi2,
                      const float* __restrict__ Wh2,
                      const float* __restrict__ bi2,
                      const float* __restrict__ bh2,
                      const float* __restrict__ Wlin,
                      const float* __restrict__ blin,
                      float* __restrict__ out) {
  __shared__ __align__(16) float lds_x[TMAIN];         // 4 KB
  __shared__ __align__(16) float lds_h1[2][64];        // [parity][u]
  __shared__ __align__(16) float lds_piK1[2][4][64];   // [par][g][u]
  __shared__ __align__(16) float lds_piK2[2][4][64];   // [par][g][u]
  __shared__ __align__(16) float lds_h2h[RING][RPAD];  // h2 history ring
  __shared__ __align__(16) float lds_wlin[64];
  __shared__ __align__(16) float lds_outbuf[64];       // feedback outputs
  __shared__ float lds_lin[2][2];                      // [par][cellwave]
  __shared__ float lds_fb[1];                          // out(1023) seed

  const int tid = threadIdx.x;
  const int s = blockIdx.x;  // sequence
  const int wid = tid >> 6;  // 0..7
  const int lane = tid & 63;
  const int half = lane >> 5;  // 0: gates {i,f}, 1: gates {g,o}
  const int l5 = lane & 31;
  const int base = (wid & 1) * 26;
  const int nu = (wid & 1) ? 25 : 26;
  const bool act = l5 < nu;
  const int u = base + (act ? l5 : 0);  // clamped unit index
  const int g0 = half * 2;
  const int koff = (wid >= 6) ? 0 : 26;  // Wi2 K-half offset

  // Stage input; zero h1 buffers (elems 51..63 too -> dotH1 pair-12 safe)
  // and ring slot RING-1 (h2(-1) = 0); stage wlin.
  for (int i = tid; i < TMAIN; i += 512) lds_x[i] = input[s * TMAIN + i];
  if (tid < 64) {
    lds_h1[0][tid] = 0.0f;
    lds_h1[1][tid] = 0.0f;
    lds_h2h[RING - 1][tid] = 0.0f;
    lds_wlin[tid] = (tid < HID) ? Wlin[tid] : 0.0f;
  }

  // ---- weights ----
  v2f w2f[2][25];  // full rows (L1 / Wh2 cell waves)
  float w50f[2] = {0.f, 0.f};
  v2f w2h[2][13];  // half rows (Wi2 waves)
  float bias[2] = {0.f, 0.f};
  float wi1g[2] = {0.f, 0.f};
  float wlin_u = 0.0f;
  float c1 = 0.0f;  // cell state (L1 in wid01, L2 in wid23)

  if (wid < 4) {
    const float* Wsel = (wid < 2) ? Wh1 : Wh2;
#pragma unroll
    for (int g = 0; g < 2; ++g) {
      const float* row = Wsel + ((g0 + g) * HID + u) * HID;
#pragma unroll
      for (int p = 0; p < 25; ++p) {
        v2f t;
        t.x = row[2 * p + 0];
        t.y = row[2 * p + 1];
        w2f[g][p] = t;
      }
      w50f[g] = row[50];
    }
    if (wid < 2) {
#pragma unroll
      for (int g = 0; g < 2; ++g) {
        bias[g] = bi1[(g0 + g) * HID + u] + bh1[(g0 + g) * HID + u];
        wi1g[g] = Wi1[(g0 + g) * HID + u];
      }
    } else {
      wlin_u = Wlin[u];  // feedback-phase butterfly weight
    }
#pragma unroll
    for (int g = 0; g < 2; ++g) {
#pragma unroll
      for (int p = 0; p < 25; ++p) asm volatile("" : "+v"(w2f[g][p]));
      asm volatile("" : "+v"(w50f[g]), "+v"(bias[g]), "+v"(wi1g[g]));
    }
    asm volatile("" : "+v"(wlin_u));
  } else {
#pragma unroll
    for (int g = 0; g < 2; ++g) {
      const float* row = Wi2 + ((g0 + g) * HID + u) * HID + koff;
      if (koff == 0) {
#pragma unroll
        for (int p = 0; p < 13; ++p) {
          v2f t;
          t.x = row[2 * p + 0];
          t.y = row[2 * p + 1];
          w2h[g][p] = t;
        }
      } else {
#pragma unroll
        for (int p = 0; p < 12; ++p) {
          v2f t;
          t.x = row[2 * p + 0];
          t.y = row[2 * p + 1];
          w2h[g][p] = t;
        }
        v2f t;
        t.x = row[24];  // K=50
        t.y = 0.0f;     // pairs with h1[51] == 0
        w2h[g][12] = t;
      }
    }
    if (koff == 26) {  // K2 waves carry bias2 (folded into piK2 writes)
#pragma unroll
      for (int g = 0; g < 2; ++g)
        bias[g] = bi2[(g0 + g) * HID + u] + bh2[(g0 + g) * HID + u];
    }
#pragma unroll
    for (int g = 0; g < 2; ++g) {
#pragma unroll
      for (int p = 0; p < 13; ++p) asm volatile("" : "+v"(w2h[g][p]));
      asm volatile("" : "+v"(bias[g]));
    }
  }
  const float blin_s = blin[0];

  __syncthreads();

  // =============== main-phase pipeline: one barrier per interval ========
  for (int k = 0; k <= TMAIN + 2; ++k) {
    if (wid < 2) {
      if (k < TMAIN) {
        // h1(k) = cell1(x(k), h1(k-1));  h1(m) lives in buffer (m+1)&1
        float x = lds_x[k];
        float a[2];
#pragma unroll
        for (int g = 0; g < 2; ++g) a[g] = fmaf(x, wi1g[g], bias[g]);
        dot1x(lds_h1[k & 1], w2f, w50f, a);
        float p0 = __shfl_xor(a[0], 32), p1 = __shfl_xor(a[1], 32);
        float gi = half ? p0 : a[0], gf = half ? p1 : a[1];
        float gg = half ? a[0] : p0, go = half ? a[1] : p1;
        c1 = fast_sigmoid(gf) * c1 + fast_sigmoid(gi) * fast_tanh(gg);
        float h = fast_sigmoid(go) * fast_tanh(c1);
        if (act && half == 0) lds_h1[(k + 1) & 1][u] = h;
      }
    } else if (wid < 4) {
      if (k >= 2 && k <= TMAIN + 1) {
        // h2(m2) = cell2(piK1(m2)+piK2(m2) + Wh2 @ h2(m2-1)); bias in piK2
        const int m2 = k - 2;
        const int pm = m2 & 1;
        float a[2];
        a[0] = lds_piK1[pm][g0 + 0][u] + lds_piK2[pm][g0 + 0][u];
        a[1] = lds_piK1[pm][g0 + 1][u] + lds_piK2[pm][g0 + 1][u];
        dot1x(&lds_h2h[(m2 - 1) & (RING - 1)][0], w2f, w50f, a);
        float p0 = __shfl_xor(a[0], 32), p1 = __shfl_xor(a[1], 32);
        float gi = half ? p0 : a[0], gf = half ? p1 : a[1];
        float gg = half ? a[0] : p0, go = half ? a[1] : p1;
        c1 = fast_sigmoid(gf) * c1 + fast_sigmoid(gi) * fast_tanh(gg);
        float h = fast_sigmoid(go) * fast_tanh(c1);
        if (act && half == 0) lds_h2h[m2 & (RING - 1)][u] = h;
      }
    } else {
      if (k >= 1 && k <= TMAIN) {
        // piK(k-1) partial: Wi2[:, koff:koff+26] @ h1(k-1)[koff:...]
        float a[2];
        dotH1(&lds_h1[k & 1][koff], w2h, a);
        const int pm = (k - 1) & 1;
        if (act) {
          if (koff == 26) {
            a[0] += bias[0];
            a[1] += bias[1];
            lds_piK2[pm][g0 + 0][u] = a[0];
            lds_piK2[pm][g0 + 1][u] = a[1];
          } else {
            lds_piK1[pm][g0 + 0][u] = a[0];
            lds_piK1[pm][g0 + 1][u] = a[1];
          }
        }
      }
      // Deferred linear head: every 64 intervals wid4 emits 64 outputs
      // (chunk c=k-66; h2(c+63) landed at interval c+65; writer this
      // interval touches slot (c+64)&127 -- disjoint from read slots).
      if (wid == 4 && k >= 66 && ((k - 66) & 63) == 0) {
        const int c = k - 66;
        const int m = c + lane;
        const float* r = &lds_h2h[m & (RING - 1)][0];
        const float4* r4 = reinterpret_cast<const float4*>(r);
        const float4* w4 = reinterpret_cast<const float4*>(lds_wlin);
        float o0 = 0.f, o1 = 0.f, o2 = 0.f, o3 = 0.f;
#pragma unroll
        for (int q = 0; q < 12; ++q) {
          float4 rv = r4[q];
          float4 wv = w4[q];
          o0 = fmaf(rv.x, wv.x, o0);
          o1 = fmaf(rv.y, wv.y, o1);
          o2 = fmaf(rv.z, wv.z, o2);
          o3 = fmaf(rv.w, wv.w, o3);
        }
        o0 = fmaf(r[48], lds_wlin[48], o0);
        o1 = fmaf(r[49], lds_wlin[49], o1);
        o2 = fmaf(r[50], lds_wlin[50], o2);
        float o = (o0 + o1) + (o2 + o3) + blin_s;
        out[s * TT + m] = o;
        if (m == TMAIN - 1) lds_fb[0] = o;  // feedback seed
      }
    }
    __syncthreads();
  }

  // =============== feedback phase: 3 sub-phases, barriered ==============
  for (int t = TMAIN; t < TT; ++t) {
    float ph[2] = {0.f, 0.f};
    // --- A: L1 cell with feedback x; cell waves pre-dot Wh2 @ h2(t-1) ---
    if (wid < 2) {
      float o;
      if (t == TMAIN) {
        o = lds_fb[0];
      } else {
        o = lds_lin[(t - 1) & 1][0] + lds_lin[(t - 1) & 1][1] + blin_s;
        if (wid == 0 && lane == 0) lds_outbuf[t - 1 - TMAIN] = o;
      }
      float a[2];
#pragma unroll
      for (int g = 0; g < 2; ++g) a[g] = fmaf(o, wi1g[g], bias[g]);
      dot1x(lds_h1[t & 1], w2f, w50f, a);
      float p0 = __shfl_xor(a[0], 32), p1 = __shfl_xor(a[1], 32);
      float gi = half ? p0 : a[0], gf = half ? p1 : a[1];
      float gg = half ? a[0] : p0, go = half ? a[1] : p1;
      c1 = fast_sigmoid(gf) * c1 + fast_sigmoid(gi) * fast_tanh(gg);
      float h = fast_sigmoid(go) * fast_tanh(c1);
      if (act && half == 0) lds_h1[(t + 1) & 1][u] = h;
    } else if (wid < 4) {
      dot1x(&lds_h2h[(t - 1) & (RING - 1)][0], w2f, w50f, ph);
    }
    __syncthreads();
    // --- B: piK halves from h1(t) ---
    if (wid >= 4) {
      float a[2];
      dotH1(&lds_h1[(t + 1) & 1][koff], w2h, a);
      const int pm = t & 1;
      if (act) {
        if (koff == 26) {
          a[0] += bias[0];
          a[1] += bias[1];
          lds_piK2[pm][g0 + 0][u] = a[0];
          lds_piK2[pm][g0 + 1][u] = a[1];
        } else {
          lds_piK1[pm][g0 + 0][u] = a[0];
          lds_piK1[pm][g0 + 1][u] = a[1];
        }
      }
    }
    __syncthreads();
    // --- C: L2 cell + linear head (butterfly on cell waves here) ---
    if (wid >= 2 && wid < 4) {
      const int pm = t & 1;
      float a[2];
      a[0] = lds_piK1[pm][g0 + 0][u] + lds_piK2[pm][g0 + 0][u] + ph[0];
      a[1] = lds_piK1[pm][g0 + 1][u] + lds_piK2[pm][g0 + 1][u] + ph[1];
      float p0 = __shfl_xor(a[0], 32), p1 = __shfl_xor(a[1], 32);
      float gi = half ? p0 : a[0], gf = half ? p1 : a[1];
      float gg = half ? a[0] : p0, go = half ? a[1] : p1;
      c1 = fast_sigmoid(gf) * c1 + fast_sigmoid(gi) * fast_tanh(gg);
      float h = fast_sigmoid(go) * fast_tanh(c1);
      float val = 0.0f;
      if (act && half == 0) {
        lds_h2h[t & (RING - 1)][u] = h;
        val = wlin_u * h;
      }
#pragma unroll
      for (int off = 16; off >= 1; off >>= 1) val += __shfl_xor(val, off);
      if (lane == 0) lds_lin[t & 1][wid - 2] = val;
    }
    __syncthreads();
  }

  // epilogue: buffer out(TT-1), then flush the 64 future outputs
  if (wid == 0 && lane == 0) {
    float o = lds_lin[(TT - 1) & 1][0] + lds_lin[(TT - 1) & 1][1] + blin_s;
    lds_outbuf[63] = o;
  }
  __syncthreads();
  if (wid == 4) out[s * TT + TMAIN + lane] = lds_outbuf[lane];
}

extern "C" void kernel_launch(void* const* d_in, const int* in_sizes, int n_in,
                              void* d_out, int out_size, void* d_ws,
                              size_t ws_size, hipStream_t stream) {
  const float* input = (const float*)d_in[0];
  const float* Wi1 = (const float*)d_in[1];
  const float* Wh1 = (const float*)d_in[2];
  const float* bi1 = (const float*)d_in[3];
  const float* bh1 = (const float*)d_in[4];
  const float* Wi2 = (const float*)d_in[5];
  const float* Wh2 = (const float*)d_in[6];
  const float* bi2 = (const float*)d_in[7];
  const float* bh2 = (const float*)d_in[8];
  const float* Wlin = (const float*)d_in[9];
  const float* blin = (const float*)d_in[10];
  float* out = (float*)d_out;

  const int B = in_sizes[0] / TMAIN;  // 512
  lstm2_persistent<<<B, 512, 0, stream>>>(input, Wi1, Wh1, bi1, bh1, Wi2,
                                          Wh2, bi2, bh2, Wlin, blin, out);
}